// Round 23
// baseline (154.760 us; speedup 1.0000x reference)
//
#include <hip/hip_runtime.h>
#include <stdint.h>

typedef __bf16 bf16x8 __attribute__((ext_vector_type(8)));
typedef float f32x4 __attribute__((ext_vector_type(4)));

__device__ __forceinline__ unsigned short f2bf(float f) {
  unsigned u = __builtin_bit_cast(unsigned, f);
  u = (u + 0x7fffu + ((u >> 16) & 1u)) >> 16;
  return (unsigned short)u;
}

__device__ __forceinline__ unsigned cvt_pk_bf16(float a, float b) {
  unsigned r;
  asm("v_cvt_pk_bf16_f32 %0, %1, %2" : "=v"(r) : "v"(a), "v"(b));
  return r;
}

__device__ __forceinline__ void gload_lds16(const unsigned short* g, unsigned short* l) {
  __builtin_amdgcn_global_load_lds(
      (__attribute__((address_space(1))) unsigned int*)g,
      (__attribute__((address_space(3))) unsigned int*)l, 16, 0, 0);
}

__device__ __forceinline__ void store_val(float* p, float v) { *p = v; }
__device__ __forceinline__ void store_val(unsigned short* p, float v) { *p = f2bf(v); }

// ---------------- fused prep: f2bf(x) + transpose(Wa, scaled Q cols) + transpose(Wp) ----
__device__ __forceinline__ void transpose_tile(const float* __restrict__ in,
                                               unsigned short* __restrict__ out,
                                               int R, int Ccols, float qscale, int qcols,
                                               int bxx, int byy,
                                               unsigned short (*t)[65]) {
  int r0 = byy * 64, c0 = bxx * 64;
  int tid = threadIdx.x;
#pragma unroll
  for (int rep = 0; rep < 16; rep++) {
    int idx = rep * 256 + tid;
    int rr = idx >> 6, cc = idx & 63;
    float v = in[(size_t)(r0 + rr) * Ccols + c0 + cc];
    if (c0 + cc < qcols) v *= qscale;
    t[rr][cc] = f2bf(v);
  }
  __syncthreads();
#pragma unroll
  for (int rep = 0; rep < 16; rep++) {
    int idx = rep * 256 + tid;
    int cc = idx >> 6, rr = idx & 63;
    out[(size_t)(c0 + cc) * R + r0 + rr] = t[rr][cc];
  }
}

__global__ __launch_bounds__(256) void prep_kernel(const float* __restrict__ x,
                                                   unsigned short* __restrict__ xb,
                                                   const float* __restrict__ Wa,
                                                   unsigned short* __restrict__ Wta,
                                                   const float* __restrict__ Wp,
                                                   unsigned short* __restrict__ Wtp,
                                                   float SC) {
  __shared__ unsigned short t[64][65];
  int bx = blockIdx.x;
  if (bx < 2048) {
    const int n = 8192 * 1024;
    const int stride = 2048 * 256 * 4;
    for (int i = (bx * 256 + threadIdx.x) * 4; i < n; i += stride) {
      float4 v = *(const float4*)(x + i);
      ushort4 o;
      o.x = f2bf(v.x); o.y = f2bf(v.y); o.z = f2bf(v.z); o.w = f2bf(v.w);
      *(ushort4*)(xb + i) = o;
    }
  } else if (bx < 2816) {
    int idx = bx - 2048;
    transpose_tile(Wa, Wta, 1024, 3072, SC, 1024, idx % 48, idx / 48, t);
  } else {
    int idx = bx - 2816;
    transpose_tile(Wp, Wtp, 1024, 1024, 1.0f, 0, idx % 16, idx / 16, t);
  }
}

// ---------------- bf16 GEMM: C[M][N] = A[M][K] * Bt[N][K]^T ----------------
// BM=128, BN=256, BK=64, 512 threads (8 waves, 2x4), per-wave 64x64 output.
// 3 LDS buffers, depth-2 prefetch, counted vmcnt(6), one barrier per K-tile.
// Issue order strictly tile-ordered. chunk^(row&7) swizzle both sides.
// 2D super-tile order: groups of GM x GN tiles (A+B working set L2-fit)
// visited n-fast within each XCD chunk.
// WRITEV: blocks with n0>=2048 (V region of qkv) write straight to the
// per-head-transposed vt[bh][d][t] layout instead of C (fuses make_vt).
template <typename OutT, bool WRITEV>
__global__ __launch_bounds__(512, 2) void gemm_bt(const unsigned short* __restrict__ A,
                                                  const unsigned short* __restrict__ Bt,
                                                  OutT* __restrict__ C, int M, int N, int K,
                                                  int ntiles, int gm, int gn,
                                                  unsigned short* __restrict__ vt) {
  __shared__ unsigned short lds3[3][24576];  // per buf: A 128x64 | B 256x64
  const int tid = threadIdx.x;
  const int wid = tid >> 6, l = tid & 63;
  const int wm = wid >> 2, wn = wid & 3;
  const int lr = l & 15, lg = l >> 4;

  int nwg = gridDim.x;
  int q8 = nwg >> 3;
  int bid = blockIdx.x;
  int bs = (bid & 7) * q8 + (bid >> 3);
  // 2D grouped mapping (bijective: ntiles%gn==0, grid%(gm*gn)==0)
  int gsz = gm * gn;
  int g = bs / gsz, r = bs % gsz;
  int ngrp_n = ntiles / gn;
  int mt = (g / ngrp_n) * gm + r / gn;
  int nt = (g % ngrp_n) * gn + r % gn;
  const int m0 = mt * 128, n0 = nt * 256;

  const int srow = tid >> 3;
  const int schunk = ((tid & 7) ^ (srow & 7)) * 8;
  const unsigned short* gA0 = A + (size_t)(m0 + srow) * K + schunk;
  const unsigned short* gB0 = Bt + (size_t)(n0 + srow) * K + schunk;
  const int wslice = wid * 512;

  int arow[4], brow[2][2], xoff[2];
#pragma unroll
  for (int m = 0; m < 4; m++) arow[m] = (wm * 64 + m * 16 + lr) * 64;
#pragma unroll
  for (int qq = 0; qq < 2; qq++)
#pragma unroll
    for (int j = 0; j < 2; j++) brow[qq][j] = 8192 + (wn * 64 + qq * 32 + j * 16 + lr) * 64;
#pragma unroll
  for (int ks = 0; ks < 2; ks++) xoff[ks] = ((ks * 4 + lg) ^ (lr & 7)) * 8;

  f32x4 acc[4][4] = {};
  const int NT = K >> 6;

  // prologue: tile 0 fully, THEN tile 1 (issue order = tile order!)
  gload_lds16(gA0, &lds3[0][wslice]);
  gload_lds16(gA0 + (size_t)64 * K, &lds3[0][4096 + wslice]);
#pragma unroll
  for (int u = 0; u < 4; u++)
    gload_lds16(gB0 + (size_t)(u * 64) * K, &lds3[0][8192 + u * 4096 + wslice]);
  gload_lds16(gA0 + 64, &lds3[1][wslice]);
  gload_lds16(gA0 + (size_t)64 * K + 64, &lds3[1][4096 + wslice]);
#pragma unroll
  for (int u = 0; u < 4; u++)
    gload_lds16(gB0 + (size_t)(u * 64) * K + 64, &lds3[1][8192 + u * 4096 + wslice]);

  int cb = 0;
  for (int t = 0; t < NT; t++) {
    if (t == NT - 1) {
      asm volatile("s_waitcnt vmcnt(0)" ::: "memory");
    } else {
      asm volatile("s_waitcnt vmcnt(6)" ::: "memory");
    }
    __builtin_amdgcn_s_barrier();
    const unsigned short* bufc = lds3[cb];
    int pb = cb + 2; if (pb >= 3) pb -= 3;
    unsigned short* bufp = lds3[pb];
    const int k2 = (t + 2) * 64;
    const bool pre = (t + 2) < NT;

    // ---- phase 0: issue A0,A1,B0 of tile t+2; compute col-half 0 ----
    if (pre) {
      gload_lds16(gA0 + k2, bufp + wslice);
      gload_lds16(gA0 + (size_t)64 * K + k2, bufp + 4096 + wslice);
      gload_lds16(gB0 + k2, bufp + 8192 + wslice);
    }
    bf16x8 af[4][2];
#pragma unroll
    for (int m = 0; m < 4; m++)
#pragma unroll
      for (int ks = 0; ks < 2; ks++)
        af[m][ks] = *(const bf16x8*)&bufc[arow[m] + xoff[ks]];
    {
      bf16x8 bq[2][2];
#pragma unroll
      for (int j = 0; j < 2; j++)
#pragma unroll
        for (int ks = 0; ks < 2; ks++)
          bq[j][ks] = *(const bf16x8*)&bufc[brow[0][j] + xoff[ks]];
      __builtin_amdgcn_s_setprio(1);
#pragma unroll
      for (int m = 0; m < 4; m++)
#pragma unroll
        for (int j = 0; j < 2; j++)
#pragma unroll
          for (int ks = 0; ks < 2; ks++)
            acc[m][j] = __builtin_amdgcn_mfma_f32_16x16x32_bf16(af[m][ks], bq[j][ks], acc[m][j], 0, 0, 0);
      __builtin_amdgcn_s_setprio(0);
    }
    // ---- phase 1: issue B1,B2,B3 of tile t+2; compute col-half 1 ----
    if (pre) {
      gload_lds16(gB0 + (size_t)64 * K + k2, bufp + 12288 + wslice);
      gload_lds16(gB0 + (size_t)128 * K + k2, bufp + 16384 + wslice);
      gload_lds16(gB0 + (size_t)192 * K + k2, bufp + 20480 + wslice);
    }
    {
      bf16x8 bq[2][2];
#pragma unroll
      for (int j = 0; j < 2; j++)
#pragma unroll
        for (int ks = 0; ks < 2; ks++)
          bq[j][ks] = *(const bf16x8*)&bufc[brow[1][j] + xoff[ks]];
      __builtin_amdgcn_s_setprio(1);
#pragma unroll
      for (int m = 0; m < 4; m++)
#pragma unroll
        for (int j = 0; j < 2; j++)
#pragma unroll
          for (int ks = 0; ks < 2; ks++)
            acc[m][2 + j] = __builtin_amdgcn_mfma_f32_16x16x32_bf16(af[m][ks], bq[j][ks], acc[m][2 + j], 0, 0, 0);
      __builtin_amdgcn_s_setprio(0);
    }
    cb = (cb == 2) ? 0 : cb + 1;
  }

  if (WRITEV && n0 >= 2048) {
    // V region: write straight to vt[bh][d][t] (bh = b*16+h), 4 t's per store.
    int hh = ((n0 - 2048) >> 6) + wn;
#pragma unroll
    for (int m = 0; m < 4; m++) {
      int row = m0 + wm * 64 + m * 16 + lg * 4;
      int bb = row >> 11, tt = row & 2047;
      size_t base = (size_t)(bb * 16 + hh) * 131072 + tt;
#pragma unroll
      for (int n = 0; n < 4; n++) {
        int d = n * 16 + lr;
        ushort4 v;
        v.x = f2bf(acc[m][n][0]); v.y = f2bf(acc[m][n][1]);
        v.z = f2bf(acc[m][n][2]); v.w = f2bf(acc[m][n][3]);
        *(ushort4*)&vt[base + (size_t)d * 2048] = v;
      }
    }
  } else {
#pragma unroll
    for (int m = 0; m < 4; m++)
#pragma unroll
      for (int n = 0; n < 4; n++)
#pragma unroll
        for (int i = 0; i < 4; i++) {
          size_t row = (size_t)(m0 + wm * 64 + m * 16 + lg * 4 + i);
          size_t col = (size_t)(n0 + wn * 64 + n * 16 + lr);
          store_val(&C[row * N + col], acc[m][n][i]);
        }
  }
}

// ---------------- flash attention, causal ----------------
// Scores pre-scaled (scale*log2e in Wq). Fixed-max softmax: P = exp2(s).
// Row sums via ones-vector MFMA. Single-buffered K/V (32 KB LDS ->
// 4 blocks/CU): per tile issue 4 gloads -> vmcnt(0) -> barrier -> compute ->
// barrier. Exposed staging latency covered by cross-block TLP.
__global__ __launch_bounds__(256, 4) void attn_kernel(const unsigned short* __restrict__ qkv,
                                                      const unsigned short* __restrict__ vt,
                                                      unsigned short* __restrict__ y) {
  __shared__ unsigned short k_lds[64 * 64];
  __shared__ unsigned short v_lds[64 * 64];
  __shared__ unsigned short p_lds[8][16 * 64];
  int tid = threadIdx.x;
  int w = tid >> 6, l = tid & 63;
  int lr = l & 15, lg = l >> 4;
  int g4 = lg * 4;
  int bh = blockIdx.x;
  int b = bh >> 4, h = bh & 15;
  int qgrp = 15 - blockIdx.y;  // heavy-first
  int q0 = qgrp * 128 + w * 32;

  char* plo = (char*)p_lds[w * 2];
  char* phi = (char*)p_lds[w * 2 + 1];

  int srow = tid >> 3;
  int schunk = (tid & 7) ^ (srow & 7);
  const unsigned short* gK0 = qkv + (size_t)(b * 2048 + srow) * 3072 + 1024 + h * 64 + schunk * 8;
  const unsigned short* gK1 = gK0 + (size_t)32 * 3072;
  const unsigned short* gV0 = vt + (size_t)bh * 131072 + (size_t)srow * 2048 + schunk * 8;
  const unsigned short* gV1 = gV0 + (size_t)32 * 2048;
  int ldsbase0 = w * 512;
  int ldsbase1 = 2048 + w * 512;

  const unsigned short* qp = qkv + (size_t)(b * 2048 + q0 + lr) * 3072 + h * 64 + lg * 8;
  bf16x8 aQ0lo = *(const bf16x8*)qp;
  bf16x8 aQ1lo = *(const bf16x8*)(qp + 32);
  bf16x8 aQ0hi = *(const bf16x8*)(qp + 16 * 3072);
  bf16x8 aQ1hi = *(const bf16x8*)(qp + 16 * 3072 + 32);

  bf16x8 vones;
#pragma unroll
  for (int i = 0; i < 8; i++) vones[i] = (__bf16)1.0f;

  f32x4 Olo[4] = {}, Ohi[4] = {};
  f32x4 OSlo = {}, OShi = {};  // row sums in O layout

  int rx = lr & 7;
  int kc0 = (lg ^ rx) * 8;
  int kc1 = ((4 + lg) ^ rx) * 8;

  int nbmax = ((qgrp * 128 + 96) >> 6) + 1;
  int kend = q0 + 31;
  int kdiag = q0 >> 6;

  for (int kb = 0; kb < nbmax; kb++) {
    int kbase = kb * 64;
    // stage tile kb into the single buffer (WAR safe: previous iteration's
    // end barrier ensures all reads of the buffer completed)
    size_t koff = (size_t)kbase * 3072;
    gload_lds16(gK0 + koff, &k_lds[ldsbase0]);
    gload_lds16(gK1 + koff, &k_lds[ldsbase1]);
    gload_lds16(gV0 + kbase, &v_lds[ldsbase0]);
    gload_lds16(gV1 + kbase, &v_lds[ldsbase1]);
    asm volatile("s_waitcnt vmcnt(0)" ::: "memory");
    __builtin_amdgcn_s_barrier();  // all waves' staging complete
    if (kbase <= kend) {
      const unsigned short* kl = k_lds;
      const unsigned short* vl = v_lds;
      f32x4 svlo[4], svhi[4];
      __builtin_amdgcn_s_setprio(1);
#pragma unroll
      for (int n = 0; n < 4; n++) {
        bf16x8 kf0 = *(const bf16x8*)&kl[(n * 16 + lr) * 64 + kc0];
        bf16x8 kf1 = *(const bf16x8*)&kl[(n * 16 + lr) * 64 + kc1];
        f32x4 z = {};
        z = __builtin_amdgcn_mfma_f32_16x16x32_bf16(kf0, aQ0lo, z, 0, 0, 0);
        z = __builtin_amdgcn_mfma_f32_16x16x32_bf16(kf1, aQ1lo, z, 0, 0, 0);
        svlo[n] = z;
        f32x4 z2 = {};
        z2 = __builtin_amdgcn_mfma_f32_16x16x32_bf16(kf0, aQ0hi, z2, 0, 0, 0);
        z2 = __builtin_amdgcn_mfma_f32_16x16x32_bf16(kf1, aQ1hi, z2, 0, 0, 0);
        svhi[n] = z2;
      }
      __builtin_amdgcn_s_setprio(0);
      if (kb == kdiag) {  // wave-uniform: mask only the diagonal tile
#pragma unroll
        for (int n = 0; n < 4; n++)
#pragma unroll
          for (int i = 0; i < 4; i++) {
            int kk = kbase + n * 16 + g4 + i;
            if (kk > q0 + lr) svlo[n][i] = -1.0e38f;
            if (kk > q0 + 16 + lr) svhi[n][i] = -1.0e38f;
          }
      }
      // --- P = exp2(s) (fixed max 0), pack to bf16 ---
      unsigned pk0lo[4], pk1lo[4], pk0hi[4], pk1hi[4];
#pragma unroll
      for (int n = 0; n < 4; n++) {
        float a0 = __builtin_amdgcn_exp2f(svlo[n][0]);
        float a1 = __builtin_amdgcn_exp2f(svlo[n][1]);
        float a2 = __builtin_amdgcn_exp2f(svlo[n][2]);
        float a3 = __builtin_amdgcn_exp2f(svlo[n][3]);
        pk0lo[n] = cvt_pk_bf16(a0, a1);
        pk1lo[n] = cvt_pk_bf16(a2, a3);
        float c0 = __builtin_amdgcn_exp2f(svhi[n][0]);
        float c1 = __builtin_amdgcn_exp2f(svhi[n][1]);
        float c2 = __builtin_amdgcn_exp2f(svhi[n][2]);
        float c3 = __builtin_amdgcn_exp2f(svhi[n][3]);
        pk0hi[n] = cvt_pk_bf16(c0, c1);
        pk1hi[n] = cvt_pk_bf16(c2, c3);
      }
#pragma unroll
      for (int n = 0; n < 4; n++) {
        int chunk = (2 * n + (lg >> 1)) ^ rx;
        int off = lr * 128 + chunk * 16 + (lg & 1) * 8;
        *(uint2*)(plo + off) = make_uint2(pk0lo[n], pk1lo[n]);
        *(uint2*)(phi + off) = make_uint2(pk0hi[n], pk1hi[n]);
      }
      bf16x8 aPlo0 = *(const bf16x8*)(plo + lr * 128 + (lg ^ rx) * 16);
      bf16x8 aPlo1 = *(const bf16x8*)(plo + lr * 128 + ((4 + lg) ^ rx) * 16);
      bf16x8 aPhi0 = *(const bf16x8*)(phi + lr * 128 + (lg ^ rx) * 16);
      bf16x8 aPhi1 = *(const bf16x8*)(phi + lr * 128 + ((4 + lg) ^ rx) * 16);
      __builtin_amdgcn_s_setprio(1);
      // row sums on the matrix pipe (same A-frags as PV)
      OSlo = __builtin_amdgcn_mfma_f32_16x16x32_bf16(aPlo0, vones, OSlo, 0, 0, 0);
      OSlo = __builtin_amdgcn_mfma_f32_16x16x32_bf16(aPlo1, vones, OSlo, 0, 0, 0);
      OShi = __builtin_amdgcn_mfma_f32_16x16x32_bf16(aPhi0, vones, OShi, 0, 0, 0);
      OShi = __builtin_amdgcn_mfma_f32_16x16x32_bf16(aPhi1, vones, OShi, 0, 0, 0);
#pragma unroll
      for (int n2 = 0; n2 < 4; n2++) {
        bf16x8 v0 = *(const bf16x8*)&vl[(n2 * 16 + lr) * 64 + kc0];
        bf16x8 v1 = *(const bf16x8*)&vl[(n2 * 16 + lr) * 64 + kc1];
        Olo[n2] = __builtin_amdgcn_mfma_f32_16x16x32_bf16(aPlo0, v0, Olo[n2], 0, 0, 0);
        Olo[n2] = __builtin_amdgcn_mfma_f32_16x16x32_bf16(aPlo1, v1, Olo[n2], 0, 0, 0);
        Ohi[n2] = __builtin_amdgcn_mfma_f32_16x16x32_bf16(aPhi0, v0, Ohi[n2], 0, 0, 0);
        Ohi[n2] = __builtin_amdgcn_mfma_f32_16x16x32_bf16(aPhi1, v1, Ohi[n2], 0, 0, 0);
      }
      __builtin_amdgcn_s_setprio(0);
    }
    __builtin_amdgcn_s_barrier();  // reads of buffer done before next stage
  }
  // --- epilogue: OSum already in O layout -> no shuffles ---
  float rl0 = 1.f / OSlo[0], rl1 = 1.f / OSlo[1], rl2 = 1.f / OSlo[2], rl3 = 1.f / OSlo[3];
  float rh0 = 1.f / OShi[0], rh1 = 1.f / OShi[1], rh2 = 1.f / OShi[2], rh3 = 1.f / OShi[3];
#pragma unroll
  for (int n2 = 0; n2 < 4; n2++) {
    size_t base = (size_t)(b * 2048 + q0 + g4) * 1024 + h * 64 + n2 * 16 + lr;
    y[base] = f2bf(Olo[n2][0] * rl0);
    y[base + 1024] = f2bf(Olo[n2][1] * rl1);
    y[base + 2048] = f2bf(Olo[n2][2] * rl2);
    y[base + 3072] = f2bf(Olo[n2][3] * rl3);
    size_t bhh = base + (size_t)16 * 1024;
    y[bhh] = f2bf(Ohi[n2][0] * rh0);
    y[bhh + 1024] = f2bf(Ohi[n2][1] * rh1);
    y[bhh + 2048] = f2bf(Ohi[n2][2] * rh2);
    y[bhh + 3072] = f2bf(Ohi[n2][3] * rh3);
  }
}

extern "C" void kernel_launch(void* const* d_in, const int* in_sizes, int n_in,
                              void* d_out, int out_size, void* d_ws, size_t ws_size,
                              hipStream_t stream) {
  const float* x = (const float*)d_in[0];
  const float* Wa = (const float*)d_in[1];
  const float* Wp = (const float*)d_in[2];
  float* out = (float*)d_out;

  char* ws = (char*)d_ws;
  size_t off = 0;
  unsigned short* xb = (unsigned short*)(ws + off);   off += (size_t)8192 * 1024 * 2;
  unsigned short* Wta = (unsigned short*)(ws + off);  off += (size_t)3072 * 1024 * 2;
  unsigned short* Wtp = (unsigned short*)(ws + off);  off += (size_t)1024 * 1024 * 2;
  unsigned short* qkvb = (unsigned short*)(ws + off); off += (size_t)8192 * 3072 * 2;
  unsigned short* vtb = (unsigned short*)(ws + off);  off += (size_t)64 * 64 * 2048 * 2;
  unsigned short* yb = (unsigned short*)(ws + off);   off += (size_t)8192 * 1024 * 2;

  const float SC = 0.125f * 1.44269504f;  // attn scale * log2(e), folded into Wq
  prep_kernel<<<3072, 256, 0, stream>>>(x, xb, Wa, Wta, Wp, Wtp, SC);
  gemm_bt<unsigned short, true><<<768, 512, 0, stream>>>(xb, Wta, qkvb, 8192, 3072, 1024, 12, 4, 6, vtb);
  attn_kernel<<<dim3(64, 16), 256, 0, stream>>>(qkvb, vtb, yb);
  gemm_bt<float, false><<<256, 512, 0, stream>>>(yb, Wtp, out, 8192, 1024, 1024, 4, 1, 4, nullptr);
}

// Round 24
// 154.408 us; speedup vs baseline: 1.0023x; 1.0023x over previous
//
#include <hip/hip_runtime.h>
#include <stdint.h>

typedef __bf16 bf16x8 __attribute__((ext_vector_type(8)));
typedef float f32x4 __attribute__((ext_vector_type(4)));

__device__ __forceinline__ unsigned short f2bf(float f) {
  unsigned u = __builtin_bit_cast(unsigned, f);
  u = (u + 0x7fffu + ((u >> 16) & 1u)) >> 16;
  return (unsigned short)u;
}

__device__ __forceinline__ unsigned cvt_pk_bf16(float a, float b) {
  unsigned r;
  asm("v_cvt_pk_bf16_f32 %0, %1, %2" : "=v"(r) : "v"(a), "v"(b));
  return r;
}

__device__ __forceinline__ void gload_lds16(const unsigned short* g, unsigned short* l) {
  __builtin_amdgcn_global_load_lds(
      (__attribute__((address_space(1))) unsigned int*)g,
      (__attribute__((address_space(3))) unsigned int*)l, 16, 0, 0);
}

__device__ __forceinline__ void store_val(float* p, float v) { *p = v; }
__device__ __forceinline__ void store_val(unsigned short* p, float v) { *p = f2bf(v); }

// ---------------- fused prep: f2bf(x) + transpose(Wa, scaled Q cols) + transpose(Wp) ----
__device__ __forceinline__ void transpose_tile(const float* __restrict__ in,
                                               unsigned short* __restrict__ out,
                                               int R, int Ccols, float qscale, int qcols,
                                               int bxx, int byy,
                                               unsigned short (*t)[65]) {
  int r0 = byy * 64, c0 = bxx * 64;
  int tid = threadIdx.x;
#pragma unroll
  for (int rep = 0; rep < 16; rep++) {
    int idx = rep * 256 + tid;
    int rr = idx >> 6, cc = idx & 63;
    float v = in[(size_t)(r0 + rr) * Ccols + c0 + cc];
    if (c0 + cc < qcols) v *= qscale;
    t[rr][cc] = f2bf(v);
  }
  __syncthreads();
#pragma unroll
  for (int rep = 0; rep < 16; rep++) {
    int idx = rep * 256 + tid;
    int cc = idx >> 6, rr = idx & 63;
    out[(size_t)(c0 + cc) * R + r0 + rr] = t[rr][cc];
  }
}

__global__ __launch_bounds__(256) void prep_kernel(const float* __restrict__ x,
                                                   unsigned short* __restrict__ xb,
                                                   const float* __restrict__ Wa,
                                                   unsigned short* __restrict__ Wta,
                                                   const float* __restrict__ Wp,
                                                   unsigned short* __restrict__ Wtp,
                                                   float SC) {
  __shared__ unsigned short t[64][65];
  int bx = blockIdx.x;
  if (bx < 2048) {
    const int n = 8192 * 1024;
    const int stride = 2048 * 256 * 4;
    for (int i = (bx * 256 + threadIdx.x) * 4; i < n; i += stride) {
      float4 v = *(const float4*)(x + i);
      ushort4 o;
      o.x = f2bf(v.x); o.y = f2bf(v.y); o.z = f2bf(v.z); o.w = f2bf(v.w);
      *(ushort4*)(xb + i) = o;
    }
  } else if (bx < 2816) {
    int idx = bx - 2048;
    transpose_tile(Wa, Wta, 1024, 3072, SC, 1024, idx % 48, idx / 48, t);
  } else {
    int idx = bx - 2816;
    transpose_tile(Wp, Wtp, 1024, 1024, 1.0f, 0, idx % 16, idx / 16, t);
  }
}

// ---------------- bf16 GEMM: C[M][N] = A[M][K] * Bt[N][K]^T ----------------
// BM=128, BN=256, BK=64, 512 threads (8 waves, 2x4), per-wave 64x64 output.
// 3 LDS buffers, depth-2 prefetch, counted vmcnt(6), one barrier per K-tile.
// Issue order strictly tile-ordered. chunk^(row&7) swizzle both sides.
// n-fast tile order: each XCD chunk covers few contiguous A-panels (L2-fit).
// WRITEV: blocks with n0>=2048 (V region of qkv) write straight to the
// per-head-transposed vt[bh][d][t] layout instead of C (fuses make_vt).
template <typename OutT, bool WRITEV>
__global__ __launch_bounds__(512, 2) void gemm_bt(const unsigned short* __restrict__ A,
                                                  const unsigned short* __restrict__ Bt,
                                                  OutT* __restrict__ C, int M, int N, int K,
                                                  int ntiles, unsigned short* __restrict__ vt) {
  __shared__ unsigned short lds3[3][24576];  // per buf: A 128x64 | B 256x64
  const int tid = threadIdx.x;
  const int wid = tid >> 6, l = tid & 63;
  const int wm = wid >> 2, wn = wid & 3;
  const int lr = l & 15, lg = l >> 4;

  int nwg = gridDim.x;
  int q8 = nwg >> 3;
  int bid = blockIdx.x;
  int bs = (bid & 7) * q8 + (bid >> 3);
  int nt = bs % ntiles, mt = bs / ntiles;  // n-fast: A-panel locality per XCD
  const int m0 = mt * 128, n0 = nt * 256;

  const int srow = tid >> 3;
  const int schunk = ((tid & 7) ^ (srow & 7)) * 8;
  const unsigned short* gA0 = A + (size_t)(m0 + srow) * K + schunk;
  const unsigned short* gB0 = Bt + (size_t)(n0 + srow) * K + schunk;
  const int wslice = wid * 512;

  int arow[4], brow[2][2], xoff[2];
#pragma unroll
  for (int m = 0; m < 4; m++) arow[m] = (wm * 64 + m * 16 + lr) * 64;
#pragma unroll
  for (int qq = 0; qq < 2; qq++)
#pragma unroll
    for (int j = 0; j < 2; j++) brow[qq][j] = 8192 + (wn * 64 + qq * 32 + j * 16 + lr) * 64;
#pragma unroll
  for (int ks = 0; ks < 2; ks++) xoff[ks] = ((ks * 4 + lg) ^ (lr & 7)) * 8;

  f32x4 acc[4][4] = {};
  const int NT = K >> 6;

  // prologue: tile 0 fully, THEN tile 1 (issue order = tile order!)
  gload_lds16(gA0, &lds3[0][wslice]);
  gload_lds16(gA0 + (size_t)64 * K, &lds3[0][4096 + wslice]);
#pragma unroll
  for (int u = 0; u < 4; u++)
    gload_lds16(gB0 + (size_t)(u * 64) * K, &lds3[0][8192 + u * 4096 + wslice]);
  gload_lds16(gA0 + 64, &lds3[1][wslice]);
  gload_lds16(gA0 + (size_t)64 * K + 64, &lds3[1][4096 + wslice]);
#pragma unroll
  for (int u = 0; u < 4; u++)
    gload_lds16(gB0 + (size_t)(u * 64) * K + 64, &lds3[1][8192 + u * 4096 + wslice]);

  int cb = 0;
  for (int t = 0; t < NT; t++) {
    if (t == NT - 1) {
      asm volatile("s_waitcnt vmcnt(0)" ::: "memory");
    } else {
      asm volatile("s_waitcnt vmcnt(6)" ::: "memory");
    }
    __builtin_amdgcn_s_barrier();
    const unsigned short* bufc = lds3[cb];
    int pb = cb + 2; if (pb >= 3) pb -= 3;
    unsigned short* bufp = lds3[pb];
    const int k2 = (t + 2) * 64;
    const bool pre = (t + 2) < NT;

    // ---- phase 0: issue A0,A1,B0 of tile t+2; compute col-half 0 ----
    if (pre) {
      gload_lds16(gA0 + k2, bufp + wslice);
      gload_lds16(gA0 + (size_t)64 * K + k2, bufp + 4096 + wslice);
      gload_lds16(gB0 + k2, bufp + 8192 + wslice);
    }
    bf16x8 af[4][2];
#pragma unroll
    for (int m = 0; m < 4; m++)
#pragma unroll
      for (int ks = 0; ks < 2; ks++)
        af[m][ks] = *(const bf16x8*)&bufc[arow[m] + xoff[ks]];
    {
      bf16x8 bq[2][2];
#pragma unroll
      for (int j = 0; j < 2; j++)
#pragma unroll
        for (int ks = 0; ks < 2; ks++)
          bq[j][ks] = *(const bf16x8*)&bufc[brow[0][j] + xoff[ks]];
      __builtin_amdgcn_s_setprio(1);
#pragma unroll
      for (int m = 0; m < 4; m++)
#pragma unroll
        for (int j = 0; j < 2; j++)
#pragma unroll
          for (int ks = 0; ks < 2; ks++)
            acc[m][j] = __builtin_amdgcn_mfma_f32_16x16x32_bf16(af[m][ks], bq[j][ks], acc[m][j], 0, 0, 0);
      __builtin_amdgcn_s_setprio(0);
    }
    // ---- phase 1: issue B1,B2,B3 of tile t+2; compute col-half 1 ----
    if (pre) {
      gload_lds16(gB0 + (size_t)64 * K + k2, bufp + 12288 + wslice);
      gload_lds16(gB0 + (size_t)128 * K + k2, bufp + 16384 + wslice);
      gload_lds16(gB0 + (size_t)192 * K + k2, bufp + 20480 + wslice);
    }
    {
      bf16x8 bq[2][2];
#pragma unroll
      for (int j = 0; j < 2; j++)
#pragma unroll
        for (int ks = 0; ks < 2; ks++)
          bq[j][ks] = *(const bf16x8*)&bufc[brow[1][j] + xoff[ks]];
      __builtin_amdgcn_s_setprio(1);
#pragma unroll
      for (int m = 0; m < 4; m++)
#pragma unroll
        for (int j = 0; j < 2; j++)
#pragma unroll
          for (int ks = 0; ks < 2; ks++)
            acc[m][2 + j] = __builtin_amdgcn_mfma_f32_16x16x32_bf16(af[m][ks], bq[j][ks], acc[m][2 + j], 0, 0, 0);
      __builtin_amdgcn_s_setprio(0);
    }
    cb = (cb == 2) ? 0 : cb + 1;
  }

  if (WRITEV && n0 >= 2048) {
    // V region: write straight to vt[bh][d][t] (bh = b*16+h), 4 t's per store.
    int hh = ((n0 - 2048) >> 6) + wn;
#pragma unroll
    for (int m = 0; m < 4; m++) {
      int row = m0 + wm * 64 + m * 16 + lg * 4;
      int bb = row >> 11, tt = row & 2047;
      size_t base = (size_t)(bb * 16 + hh) * 131072 + tt;
#pragma unroll
      for (int n = 0; n < 4; n++) {
        int d = n * 16 + lr;
        ushort4 v;
        v.x = f2bf(acc[m][n][0]); v.y = f2bf(acc[m][n][1]);
        v.z = f2bf(acc[m][n][2]); v.w = f2bf(acc[m][n][3]);
        *(ushort4*)&vt[base + (size_t)d * 2048] = v;
      }
    }
  } else {
#pragma unroll
    for (int m = 0; m < 4; m++)
#pragma unroll
      for (int n = 0; n < 4; n++)
#pragma unroll
        for (int i = 0; i < 4; i++) {
          size_t row = (size_t)(m0 + wm * 64 + m * 16 + lg * 4 + i);
          size_t col = (size_t)(n0 + wn * 64 + n * 16 + lr);
          store_val(&C[row * N + col], acc[m][n][i]);
        }
  }
}

// ---------------- flash attention, causal ----------------
// Scores pre-scaled (scale*log2e in Wq). Fixed-max softmax: P = exp2(s).
// Row sums via ones-vector MFMA. Single-buffered K/V (32 KB LDS ->
// 4 blocks/CU): per tile issue 4 gloads -> vmcnt(0) -> barrier -> compute ->
// barrier. Exposed staging latency covered by cross-block TLP.
__global__ __launch_bounds__(256, 4) void attn_kernel(const unsigned short* __restrict__ qkv,
                                                      const unsigned short* __restrict__ vt,
                                                      unsigned short* __restrict__ y) {
  __shared__ unsigned short k_lds[64 * 64];
  __shared__ unsigned short v_lds[64 * 64];
  __shared__ unsigned short p_lds[8][16 * 64];
  int tid = threadIdx.x;
  int w = tid >> 6, l = tid & 63;
  int lr = l & 15, lg = l >> 4;
  int g4 = lg * 4;
  int bh = blockIdx.x;
  int b = bh >> 4, h = bh & 15;
  int qgrp = 15 - blockIdx.y;  // heavy-first
  int q0 = qgrp * 128 + w * 32;

  char* plo = (char*)p_lds[w * 2];
  char* phi = (char*)p_lds[w * 2 + 1];

  int srow = tid >> 3;
  int schunk = (tid & 7) ^ (srow & 7);
  const unsigned short* gK0 = qkv + (size_t)(b * 2048 + srow) * 3072 + 1024 + h * 64 + schunk * 8;
  const unsigned short* gK1 = gK0 + (size_t)32 * 3072;
  const unsigned short* gV0 = vt + (size_t)bh * 131072 + (size_t)srow * 2048 + schunk * 8;
  const unsigned short* gV1 = gV0 + (size_t)32 * 2048;
  int ldsbase0 = w * 512;
  int ldsbase1 = 2048 + w * 512;

  const unsigned short* qp = qkv + (size_t)(b * 2048 + q0 + lr) * 3072 + h * 64 + lg * 8;
  bf16x8 aQ0lo = *(const bf16x8*)qp;
  bf16x8 aQ1lo = *(const bf16x8*)(qp + 32);
  bf16x8 aQ0hi = *(const bf16x8*)(qp + 16 * 3072);
  bf16x8 aQ1hi = *(const bf16x8*)(qp + 16 * 3072 + 32);

  bf16x8 vones;
#pragma unroll
  for (int i = 0; i < 8; i++) vones[i] = (__bf16)1.0f;

  f32x4 Olo[4] = {}, Ohi[4] = {};
  f32x4 OSlo = {}, OShi = {};  // row sums in O layout

  int rx = lr & 7;
  int kc0 = (lg ^ rx) * 8;
  int kc1 = ((4 + lg) ^ rx) * 8;

  int nbmax = ((qgrp * 128 + 96) >> 6) + 1;
  int kend = q0 + 31;
  int kdiag = q0 >> 6;

  for (int kb = 0; kb < nbmax; kb++) {
    int kbase = kb * 64;
    // stage tile kb into the single buffer (WAR safe: previous iteration's
    // end barrier ensures all reads of the buffer completed)
    size_t koff = (size_t)kbase * 3072;
    gload_lds16(gK0 + koff, &k_lds[ldsbase0]);
    gload_lds16(gK1 + koff, &k_lds[ldsbase1]);
    gload_lds16(gV0 + kbase, &v_lds[ldsbase0]);
    gload_lds16(gV1 + kbase, &v_lds[ldsbase1]);
    asm volatile("s_waitcnt vmcnt(0)" ::: "memory");
    __builtin_amdgcn_s_barrier();  // all waves' staging complete
    if (kbase <= kend) {
      const unsigned short* kl = k_lds;
      const unsigned short* vl = v_lds;
      f32x4 svlo[4], svhi[4];
      __builtin_amdgcn_s_setprio(1);
#pragma unroll
      for (int n = 0; n < 4; n++) {
        bf16x8 kf0 = *(const bf16x8*)&kl[(n * 16 + lr) * 64 + kc0];
        bf16x8 kf1 = *(const bf16x8*)&kl[(n * 16 + lr) * 64 + kc1];
        f32x4 z = {};
        z = __builtin_amdgcn_mfma_f32_16x16x32_bf16(kf0, aQ0lo, z, 0, 0, 0);
        z = __builtin_amdgcn_mfma_f32_16x16x32_bf16(kf1, aQ1lo, z, 0, 0, 0);
        svlo[n] = z;
        f32x4 z2 = {};
        z2 = __builtin_amdgcn_mfma_f32_16x16x32_bf16(kf0, aQ0hi, z2, 0, 0, 0);
        z2 = __builtin_amdgcn_mfma_f32_16x16x32_bf16(kf1, aQ1hi, z2, 0, 0, 0);
        svhi[n] = z2;
      }
      __builtin_amdgcn_s_setprio(0);
      if (kb == kdiag) {  // wave-uniform: mask only the diagonal tile
#pragma unroll
        for (int n = 0; n < 4; n++)
#pragma unroll
          for (int i = 0; i < 4; i++) {
            int kk = kbase + n * 16 + g4 + i;
            if (kk > q0 + lr) svlo[n][i] = -1.0e38f;
            if (kk > q0 + 16 + lr) svhi[n][i] = -1.0e38f;
          }
      }
      // --- P = exp2(s) (fixed max 0), pack to bf16 ---
      unsigned pk0lo[4], pk1lo[4], pk0hi[4], pk1hi[4];
#pragma unroll
      for (int n = 0; n < 4; n++) {
        float a0 = __builtin_amdgcn_exp2f(svlo[n][0]);
        float a1 = __builtin_amdgcn_exp2f(svlo[n][1]);
        float a2 = __builtin_amdgcn_exp2f(svlo[n][2]);
        float a3 = __builtin_amdgcn_exp2f(svlo[n][3]);
        pk0lo[n] = cvt_pk_bf16(a0, a1);
        pk1lo[n] = cvt_pk_bf16(a2, a3);
        float c0 = __builtin_amdgcn_exp2f(svhi[n][0]);
        float c1 = __builtin_amdgcn_exp2f(svhi[n][1]);
        float c2 = __builtin_amdgcn_exp2f(svhi[n][2]);
        float c3 = __builtin_amdgcn_exp2f(svhi[n][3]);
        pk0hi[n] = cvt_pk_bf16(c0, c1);
        pk1hi[n] = cvt_pk_bf16(c2, c3);
      }
#pragma unroll
      for (int n = 0; n < 4; n++) {
        int chunk = (2 * n + (lg >> 1)) ^ rx;
        int off = lr * 128 + chunk * 16 + (lg & 1) * 8;
        *(uint2*)(plo + off) = make_uint2(pk0lo[n], pk1lo[n]);
        *(uint2*)(phi + off) = make_uint2(pk0hi[n], pk1hi[n]);
      }
      bf16x8 aPlo0 = *(const bf16x8*)(plo + lr * 128 + (lg ^ rx) * 16);
      bf16x8 aPlo1 = *(const bf16x8*)(plo + lr * 128 + ((4 + lg) ^ rx) * 16);
      bf16x8 aPhi0 = *(const bf16x8*)(phi + lr * 128 + (lg ^ rx) * 16);
      bf16x8 aPhi1 = *(const bf16x8*)(phi + lr * 128 + ((4 + lg) ^ rx) * 16);
      __builtin_amdgcn_s_setprio(1);
      // row sums on the matrix pipe (same A-frags as PV)
      OSlo = __builtin_amdgcn_mfma_f32_16x16x32_bf16(aPlo0, vones, OSlo, 0, 0, 0);
      OSlo = __builtin_amdgcn_mfma_f32_16x16x32_bf16(aPlo1, vones, OSlo, 0, 0, 0);
      OShi = __builtin_amdgcn_mfma_f32_16x16x32_bf16(aPhi0, vones, OShi, 0, 0, 0);
      OShi = __builtin_amdgcn_mfma_f32_16x16x32_bf16(aPhi1, vones, OShi, 0, 0, 0);
#pragma unroll
      for (int n2 = 0; n2 < 4; n2++) {
        bf16x8 v0 = *(const bf16x8*)&vl[(n2 * 16 + lr) * 64 + kc0];
        bf16x8 v1 = *(const bf16x8*)&vl[(n2 * 16 + lr) * 64 + kc1];
        Olo[n2] = __builtin_amdgcn_mfma_f32_16x16x32_bf16(aPlo0, v0, Olo[n2], 0, 0, 0);
        Olo[n2] = __builtin_amdgcn_mfma_f32_16x16x32_bf16(aPlo1, v1, Olo[n2], 0, 0, 0);
        Ohi[n2] = __builtin_amdgcn_mfma_f32_16x16x32_bf16(aPhi0, v0, Ohi[n2], 0, 0, 0);
        Ohi[n2] = __builtin_amdgcn_mfma_f32_16x16x32_bf16(aPhi1, v1, Ohi[n2], 0, 0, 0);
      }
      __builtin_amdgcn_s_setprio(0);
    }
    __builtin_amdgcn_s_barrier();  // reads of buffer done before next stage
  }
  // --- epilogue: OSum already in O layout -> no shuffles ---
  float rl0 = 1.f / OSlo[0], rl1 = 1.f / OSlo[1], rl2 = 1.f / OSlo[2], rl3 = 1.f / OSlo[3];
  float rh0 = 1.f / OShi[0], rh1 = 1.f / OShi[1], rh2 = 1.f / OShi[2], rh3 = 1.f / OShi[3];
#pragma unroll
  for (int n2 = 0; n2 < 4; n2++) {
    size_t base = (size_t)(b * 2048 + q0 + g4) * 1024 + h * 64 + n2 * 16 + lr;
    y[base] = f2bf(Olo[n2][0] * rl0);
    y[base + 1024] = f2bf(Olo[n2][1] * rl1);
    y[base + 2048] = f2bf(Olo[n2][2] * rl2);
    y[base + 3072] = f2bf(Olo[n2][3] * rl3);
    size_t bhh = base + (size_t)16 * 1024;
    y[bhh] = f2bf(Ohi[n2][0] * rh0);
    y[bhh + 1024] = f2bf(Ohi[n2][1] * rh1);
    y[bhh + 2048] = f2bf(Ohi[n2][2] * rh2);
    y[bhh + 3072] = f2bf(Ohi[n2][3] * rh3);
  }
}

extern "C" void kernel_launch(void* const* d_in, const int* in_sizes, int n_in,
                              void* d_out, int out_size, void* d_ws, size_t ws_size,
                              hipStream_t stream) {
  const float* x = (const float*)d_in[0];
  const float* Wa = (const float*)d_in[1];
  const float* Wp = (const float*)d_in[2];
  float* out = (float*)d_out;

  char* ws = (char*)d_ws;
  size_t off = 0;
  unsigned short* xb = (unsigned short*)(ws + off);   off += (size_t)8192 * 1024 * 2;
  unsigned short* Wta = (unsigned short*)(ws + off);  off += (size_t)3072 * 1024 * 2;
  unsigned short* Wtp = (unsigned short*)(ws + off);  off += (size_t)1024 * 1024 * 2;
  unsigned short* qkvb = (unsigned short*)(ws + off); off += (size_t)8192 * 3072 * 2;
  unsigned short* vtb = (unsigned short*)(ws + off);  off += (size_t)64 * 64 * 2048 * 2;
  unsigned short* yb = (unsigned short*)(ws + off);   off += (size_t)8192 * 1024 * 2;

  const float SC = 0.125f * 1.44269504f;  // attn scale * log2(e), folded into Wq
  prep_kernel<<<3072, 256, 0, stream>>>(x, xb, Wa, Wta, Wp, Wtp, SC);
  gemm_bt<unsigned short, true><<<768, 512, 0, stream>>>(xb, Wta, qkvb, 8192, 3072, 1024, 12, vtb);
  attn_kernel<<<dim3(64, 16), 256, 0, stream>>>(qkvb, vtb, yb);
  gemm_bt<float, false><<<256, 512, 0, stream>>>(yb, Wtp, out, 8192, 1024, 1024, 4, nullptr);
}